// Round 1
// baseline (4250.813 us; speedup 1.0000x reference)
//
#include <hip/hip_runtime.h>
#include <hip/hip_bf16.h>

#define N_NODES 100000
#define N_EDGES 1600000
#define DIM 64
#define NL 4
#define NG 1024

// ---------------------------------------------------------------------------
// Workspace layout (floats):
//   h      @ 0                : N*64   node features
//   agg    @ 6.4M             : N*64   scatter target / z2 output (reused)
//   stats  @ 12.8M            : 768    [sum1(128) sq1(128) a1(128) c1(128)
//                                       sum2(64) sq2(64) a2(64) c2(64)]
//   pooled @ stats+768        : 1024*64
//   cnt    @ pooled+65536     : 1024
// total ~51.5 MB
// ---------------------------------------------------------------------------

__global__ void k_atom_embed(const int* __restrict__ x, const float* __restrict__ emb,
                             float* __restrict__ h) {
  int n = blockIdx.x * 4 + (threadIdx.x >> 6);
  int d = threadIdx.x & 63;
  if (n >= N_NODES) return;
  const int* xr = x + n * 9;
  float acc = 0.f;
#pragma unroll
  for (int c = 0; c < 9; ++c) acc += emb[(c * 100 + xr[c]) * 64 + d];
  h[n * 64 + d] = acc;
}

// one wave = one edge's 64 dims; 8 edges per wave, 4 waves per block
__global__ void k_edge_scatter(const int* __restrict__ ei, const int* __restrict__ ea,
                               const float* __restrict__ bond, const float* __restrict__ h,
                               float* __restrict__ agg) {
  __shared__ float sb[3 * 8 * 64];  // bond table for this layer, 6 KB
  for (int i = threadIdx.x; i < 1536; i += 256) sb[i] = bond[i];
  __syncthreads();
  int wave = threadIdx.x >> 6;
  int d = threadIdx.x & 63;
  int e0 = (blockIdx.x * 4 + wave) * 8;
#pragma unroll
  for (int i = 0; i < 8; ++i) {
    int e = e0 + i;
    if (e >= N_EDGES) break;
    int s = ei[e];             // scatter index (segment_sum over src)
    int t = ei[N_EDGES + e];   // gather index (h[dst])
    int a0 = ea[e * 3], a1 = ea[e * 3 + 1], a2 = ea[e * 3 + 2];
    float ef = sb[a0 * 64 + d] + sb[(8 + a1) * 64 + d] + sb[(16 + a2) * 64 + d];
    float m = fmaxf(h[t * 64 + d] + ef, 0.f);
    atomicAdd(&agg[s * 64 + d], m);
  }
}

// z = (1+eps)*h + agg; z1 = z@W1 + b1; accumulate per-column sum/sumsq only.
// 64 nodes/block, thread = (j in 0..127) x (half in 0..1)
__global__ void k_mm1_stats(const float* __restrict__ h, const float* __restrict__ agg,
                            const float* __restrict__ W1, const float* __restrict__ b1,
                            const float* __restrict__ epsp,
                            float* __restrict__ sum1, float* __restrict__ sq1) {
  __shared__ float zl[4096];
  __shared__ float red[256];
  int tid = threadIdx.x;
  long nb = (long)blockIdx.x * 64;
  float ep = 1.0f + epsp[0];
  for (int i = tid; i < 4096; i += 256) {
    long g = nb * 64 + i;
    zl[i] = (g < (long)N_NODES * 64) ? fmaf(ep, h[g], agg[g]) : 0.f;
  }
  int j = tid & 127, half = tid >> 7;
  float w[64];
#pragma unroll
  for (int k = 0; k < 64; ++k) w[k] = W1[k * 128 + j];
  float bj = b1[j];
  __syncthreads();
  float s = 0.f, q = 0.f;
  for (int it = 0; it < 32; ++it) {
    int n = it * 2 + half;
    if (nb + n >= N_NODES) break;
    float acc = bj;
#pragma unroll
    for (int k = 0; k < 64; ++k) acc = fmaf(zl[n * 64 + k], w[k], acc);
    s += acc;
    q = fmaf(acc, acc, q);
  }
  red[tid] = s;
  __syncthreads();
  if (tid < 128) atomicAdd(&sum1[j], red[tid] + red[tid + 128]);
  __syncthreads();
  red[tid] = q;
  __syncthreads();
  if (tid < 128) atomicAdd(&sq1[j], red[tid] + red[tid + 128]);
}

__global__ void k_finalize(const float* __restrict__ sum, const float* __restrict__ sq,
                           const float* __restrict__ g, const float* __restrict__ b,
                           float* __restrict__ a, float* __restrict__ c) {
  int j = threadIdx.x;
  const float inv = 1.0f / (float)N_NODES;
  float m = sum[j] * inv;
  float v = sq[j] * inv - m * m;
  float r = rsqrtf(v + 1e-5f);
  float aa = g[j] * r;
  a[j] = aa;
  c[j] = fmaf(-m, aa, b[j]);
}

// recompute z1 = bn1(z@W1+b1) (affine a1,c1), relu, then z2 = z1@W2 + b2.
// z2 written in-place over agg (row-local, safe). Accumulates stats2.
__global__ void k_mm2(const float* h, const float* agg,
                      const float* W1, const float* b1,
                      const float* a1, const float* c1,
                      const float* W2, const float* b2,
                      const float* epsp,
                      float* z2, float* sum2, float* sq2) {
  __shared__ float zl[4096];
  __shared__ float z1l[8192];
  __shared__ float red[256];
  int tid = threadIdx.x;
  long nb = (long)blockIdx.x * 64;
  float ep = 1.0f + epsp[0];
  for (int i = tid; i < 4096; i += 256) {
    long g = nb * 64 + i;
    zl[i] = (g < (long)N_NODES * 64) ? fmaf(ep, h[g], agg[g]) : 0.f;
  }
  {
    int j = tid & 127, half = tid >> 7;
    float w[64];
#pragma unroll
    for (int k = 0; k < 64; ++k) w[k] = W1[k * 128 + j];
    float bj = b1[j], aj = a1[j], cj = c1[j];
    __syncthreads();
    for (int it = 0; it < 32; ++it) {
      int n = it * 2 + half;
      float acc = bj;
#pragma unroll
      for (int k = 0; k < 64; ++k) acc = fmaf(zl[n * 64 + k], w[k], acc);
      z1l[n * 128 + j] = fmaxf(fmaf(acc, aj, cj), 0.f);
    }
  }
  __syncthreads();
  int j = tid & 63, q4 = tid >> 6;
  float bj = b2[j];
  float accB[16];
#pragma unroll
  for (int it = 0; it < 16; ++it) accB[it] = bj;
  for (int kc = 0; kc < 2; ++kc) {
    float w[64];
#pragma unroll
    for (int k = 0; k < 64; ++k) w[k] = W2[(kc * 64 + k) * 64 + j];
#pragma unroll
    for (int it = 0; it < 16; ++it) {
      int n = it * 4 + q4;
#pragma unroll
      for (int k = 0; k < 64; ++k)
        accB[it] = fmaf(z1l[n * 128 + kc * 64 + k], w[k], accB[it]);
    }
  }
  float s = 0.f, q = 0.f;
#pragma unroll
  for (int it = 0; it < 16; ++it) {
    int n = it * 4 + q4;
    long gn = nb + n;
    if (gn < N_NODES) {
      float v = accB[it];
      z2[gn * 64 + j] = v;
      s += v;
      q = fmaf(v, v, q);
    }
  }
  red[tid] = s;
  __syncthreads();
  if (tid < 64) atomicAdd(&sum2[j], red[tid] + red[tid + 64] + red[tid + 128] + red[tid + 192]);
  __syncthreads();
  red[tid] = q;
  __syncthreads();
  if (tid < 64) atomicAdd(&sq2[j], red[tid] + red[tid + 64] + red[tid + 128] + red[tid + 192]);
}

__global__ void k_bn2(const float* __restrict__ z2, const float* __restrict__ a2,
                      const float* __restrict__ c2, float* __restrict__ h,
                      int do_relu, int do_pool, const int* __restrict__ batch,
                      float* __restrict__ pooled, float* __restrict__ cnt) {
  int n = blockIdx.x * 4 + (threadIdx.x >> 6);
  int d = threadIdx.x & 63;
  if (n >= N_NODES) return;
  float v = fmaf(z2[n * 64 + d], a2[d], c2[d]);
  if (do_relu) v = fmaxf(v, 0.f);
  h[n * 64 + d] = v;
  if (do_pool) {
    int g = batch[n];
    atomicAdd(&pooled[g * 64 + d], v);
    if (d == 0) atomicAdd(&cnt[g], 1.0f);
  }
}

__global__ void k_div(const float* __restrict__ pooled, const float* __restrict__ cnt,
                      float* __restrict__ out) {
  int g = blockIdx.x, d = threadIdx.x;
  out[g * 64 + d] = pooled[g * 64 + d] / (cnt[g] + 1e-9f);
}

extern "C" void kernel_launch(void* const* d_in, const int* in_sizes, int n_in,
                              void* d_out, int out_size, void* d_ws, size_t ws_size,
                              hipStream_t stream) {
  const int* x = (const int*)d_in[0];
  const int* ea = (const int*)d_in[1];
  const int* ei = (const int*)d_in[2];
  const int* batch = (const int*)d_in[3];
  const float* atom_emb = (const float*)d_in[4];
  const float* bond_emb = (const float*)d_in[5];
  const float* W1 = (const float*)d_in[6];
  const float* b1 = (const float*)d_in[7];
  const float* g1 = (const float*)d_in[8];
  const float* be1 = (const float*)d_in[9];
  const float* W2 = (const float*)d_in[10];
  const float* b2 = (const float*)d_in[11];
  const float* eps = (const float*)d_in[12];
  const float* bn_g = (const float*)d_in[13];
  const float* bn_b = (const float*)d_in[14];

  float* w = (float*)d_ws;
  float* h = w;
  float* agg = w + (size_t)N_NODES * 64;
  float* stats = agg + (size_t)N_NODES * 64;
  float* pooled = stats + 768;
  float* cnt = pooled + (size_t)NG * 64;

  hipMemsetAsync(pooled, 0, (NG * 64 + NG) * sizeof(float), stream);

  k_atom_embed<<<N_NODES / 4, 256, 0, stream>>>(x, atom_emb, h);

  for (int l = 0; l < NL; ++l) {
    float* sum1 = stats;
    float* sq1 = stats + 128;
    float* a1 = stats + 256;
    float* c1 = stats + 384;
    float* sum2 = stats + 512;
    float* sq2 = stats + 576;
    float* a2 = stats + 640;
    float* c2 = stats + 704;

    hipMemsetAsync(agg, 0, (size_t)N_NODES * 64 * sizeof(float), stream);
    hipMemsetAsync(stats, 0, 256 * sizeof(float), stream);   // sum1, sq1
    hipMemsetAsync(sum2, 0, 128 * sizeof(float), stream);    // sum2, sq2

    k_edge_scatter<<<(N_EDGES + 31) / 32, 256, 0, stream>>>(
        ei, ea, bond_emb + (size_t)l * 1536, h, agg);
    k_mm1_stats<<<(N_NODES + 63) / 64, 256, 0, stream>>>(
        h, agg, W1 + (size_t)l * 64 * 128, b1 + l * 128, eps + l, sum1, sq1);
    k_finalize<<<1, 128, 0, stream>>>(sum1, sq1, g1 + l * 128, be1 + l * 128, a1, c1);
    k_mm2<<<(N_NODES + 63) / 64, 256, 0, stream>>>(
        h, agg, W1 + (size_t)l * 64 * 128, b1 + l * 128, a1, c1,
        W2 + (size_t)l * 128 * 64, b2 + l * 64, eps + l, agg, sum2, sq2);
    k_finalize<<<1, 64, 0, stream>>>(sum2, sq2, bn_g + l * 64, bn_b + l * 64, a2, c2);
    k_bn2<<<N_NODES / 4, 256, 0, stream>>>(agg, a2, c2, h, (l != NL - 1) ? 1 : 0,
                                           (l == NL - 1) ? 1 : 0, batch, pooled, cnt);
  }
  k_div<<<NG, 64, 0, stream>>>(pooled, cnt, (float*)d_out);
}